// Round 1
// baseline (1136.622 us; speedup 1.0000x reference)
//
#include <hip/hip_runtime.h>
#include <math.h>

#define N_NODES 100000
#define N_EDGES 1600000
#define N_POSTS 10000
#define ND 128
#define H 64

__device__ __forceinline__ float bcastf(float v, int lane) {
  return __builtin_bit_cast(float, __builtin_amdgcn_readlane(__builtin_bit_cast(int, v), lane));
}

__device__ __forceinline__ int load_idx(const void* p, long long i, int is64) {
  if (is64) return (int)((const long long*)p)[i];
  return ((const int*)p)[i];
}

// Detect whether integer inputs arrived as int64 (odd 32-bit words all zero)
__global__ void detect_kernel(const void* __restrict__ eidx, int* __restrict__ flag) {
  int t = threadIdx.x; // 64 threads
  int v = ((const int*)eidx)[2 * t + 1];
  unsigned long long b = __ballot(v != 0);
  if (t == 0) flag[0] = (b == 0ULL) ? 1 : 0; // 1 => int64 layout
}

// Per-node: node_emb = relu(nf @ Wn.T + bn); T2 = node_emb @ Wc[:, :H].T + bc
// acc <- node_emb (messages accumulate into it), T2 stored separately.
__global__ void __launch_bounds__(256, 2) node_kernel(
    const float* __restrict__ nf, const float* __restrict__ Wn,
    const float* __restrict__ bn, const float* __restrict__ Wc,
    const float* __restrict__ bc, float* __restrict__ acc,
    float* __restrict__ T2) {
  const int lane = threadIdx.x & 63;
  const int wid = blockIdx.x * (blockDim.x >> 6) + (threadIdx.x >> 6);
  const int nw = gridDim.x * (blockDim.x >> 6);

  float wn[ND]; // W_node row `lane` (lane j owns output channel j)
#pragma unroll
  for (int i = 0; i < ND / 4; ++i) {
    float4 v = ((const float4*)(Wn + lane * ND))[i];
    wn[4 * i] = v.x; wn[4 * i + 1] = v.y; wn[4 * i + 2] = v.z; wn[4 * i + 3] = v.w;
  }
  float wc[H]; // W_conv row `lane`, first half (node part)
#pragma unroll
  for (int i = 0; i < H / 4; ++i) {
    float4 v = ((const float4*)(Wc + lane * 2 * H))[i];
    wc[4 * i] = v.x; wc[4 * i + 1] = v.y; wc[4 * i + 2] = v.z; wc[4 * i + 3] = v.w;
  }
  const float bnl = bn[lane];
  const float bcl = bc[lane];

  for (int n = wid; n < N_NODES; n += nw) {
    const float xa = nf[(long long)n * ND + lane];
    const float xb = nf[(long long)n * ND + 64 + lane];
    float a0 = 0.f, a1 = 0.f, a2 = 0.f, a3 = 0.f;
#pragma unroll
    for (int k = 0; k < 64; k += 4) {
      a0 = fmaf(bcastf(xa, k + 0), wn[k + 0], a0);
      a1 = fmaf(bcastf(xa, k + 1), wn[k + 1], a1);
      a2 = fmaf(bcastf(xa, k + 2), wn[k + 2], a2);
      a3 = fmaf(bcastf(xa, k + 3), wn[k + 3], a3);
    }
#pragma unroll
    for (int k = 0; k < 64; k += 4) {
      a0 = fmaf(bcastf(xb, k + 0), wn[64 + k + 0], a0);
      a1 = fmaf(bcastf(xb, k + 1), wn[64 + k + 1], a1);
      a2 = fmaf(bcastf(xb, k + 2), wn[64 + k + 2], a2);
      a3 = fmaf(bcastf(xb, k + 3), wn[64 + k + 3], a3);
    }
    float e = fmaxf(a0 + a1 + a2 + a3 + bnl, 0.f);

    float t0 = 0.f, t1 = 0.f, t2 = 0.f, t3 = 0.f;
#pragma unroll
    for (int j = 0; j < 64; j += 4) {
      t0 = fmaf(bcastf(e, j + 0), wc[j + 0], t0);
      t1 = fmaf(bcastf(e, j + 1), wc[j + 1], t1);
      t2 = fmaf(bcastf(e, j + 2), wc[j + 2], t2);
      t3 = fmaf(bcastf(e, j + 3), wc[j + 3], t3);
    }
    float t = t0 + t1 + t2 + t3 + bcl;

    acc[(long long)n * H + lane] = e;
    T2[(long long)n * H + lane] = t;
  }
}

// Per-edge: he = relu(ea @ We.T + be); m = he @ Wc[:, H:].T + T2[src];
// atomicAdd into acc[dst].
__global__ void __launch_bounds__(256, 3) edge_kernel(
    const void* __restrict__ eidx, const float* __restrict__ ea,
    const float* __restrict__ We, const float* __restrict__ be,
    const float* __restrict__ Wc, const float* __restrict__ T2,
    float* __restrict__ acc, const int* __restrict__ flag) {
  const int lane = threadIdx.x & 63;
  const int wid = blockIdx.x * (blockDim.x >> 6) + (threadIdx.x >> 6);
  const int nw = gridDim.x * (blockDim.x >> 6);
  const int is64 = flag[0];

  float we[H]; // W_edge row `lane`
#pragma unroll
  for (int i = 0; i < H / 4; ++i) {
    float4 v = ((const float4*)(We + lane * H))[i];
    we[4 * i] = v.x; we[4 * i + 1] = v.y; we[4 * i + 2] = v.z; we[4 * i + 3] = v.w;
  }
  float wce[H]; // W_conv row `lane`, second half (edge part)
#pragma unroll
  for (int i = 0; i < H / 4; ++i) {
    float4 v = ((const float4*)(Wc + lane * 2 * H + H))[i];
    wce[4 * i] = v.x; wce[4 * i + 1] = v.y; wce[4 * i + 2] = v.z; wce[4 * i + 3] = v.w;
  }
  const float bel = be[lane];

  for (int e = wid; e < N_EDGES; e += nw) {
    const int src = load_idx(eidx, e, is64);
    const int dst = load_idx(eidx, (long long)N_EDGES + e, is64);
    const float t2v = T2[(long long)src * H + lane]; // early: hide gather latency
    const float eav = ea[(long long)e * H + lane];

    float a0 = 0.f, a1 = 0.f, a2 = 0.f, a3 = 0.f;
#pragma unroll
    for (int k = 0; k < H; k += 4) {
      a0 = fmaf(bcastf(eav, k + 0), we[k + 0], a0);
      a1 = fmaf(bcastf(eav, k + 1), we[k + 1], a1);
      a2 = fmaf(bcastf(eav, k + 2), we[k + 2], a2);
      a3 = fmaf(bcastf(eav, k + 3), we[k + 3], a3);
    }
    float h = fmaxf(a0 + a1 + a2 + a3 + bel, 0.f);

    float m0 = 0.f, m1 = 0.f, m2 = 0.f, m3 = 0.f;
#pragma unroll
    for (int j = 0; j < H; j += 4) {
      m0 = fmaf(bcastf(h, j + 0), wce[j + 0], m0);
      m1 = fmaf(bcastf(h, j + 1), wce[j + 1], m1);
      m2 = fmaf(bcastf(h, j + 2), wce[j + 2], m2);
      m3 = fmaf(bcastf(h, j + 3), wce[j + 3], m3);
    }
    float m = m0 + m1 + m2 + m3 + t2v;

    atomicAdd(&acc[(long long)dst * H + lane], m);
  }
}

// Per-post: logit = dot(acc[idx], W_out) + b_out; out = sigmoid(logit)
__global__ void __launch_bounds__(256) out_kernel(
    const void* __restrict__ pidx, const float* __restrict__ acc,
    const float* __restrict__ Wo, const float* __restrict__ bo,
    float* __restrict__ out, const int* __restrict__ flag) {
  const int lane = threadIdx.x & 63;
  const int w = blockIdx.x * (blockDim.x >> 6) + (threadIdx.x >> 6);
  if (w >= N_POSTS) return;
  const int is64 = flag[0];
  const int idx = load_idx(pidx, w, is64);
  float v = acc[(long long)idx * H + lane] * Wo[lane];
#pragma unroll
  for (int s = 32; s > 0; s >>= 1) v += __shfl_xor(v, s, 64);
  if (lane == 0) {
    float logit = v + bo[0];
    out[w] = 1.f / (1.f + expf(-logit));
  }
}

extern "C" void kernel_launch(void* const* d_in, const int* in_sizes, int n_in,
                              void* d_out, int out_size, void* d_ws, size_t ws_size,
                              hipStream_t stream) {
  const float* nf  = (const float*)d_in[0];
  const void*  eidx = d_in[1];
  const float* ea  = (const float*)d_in[2];
  const void*  pidx = d_in[3];
  const float* Wn  = (const float*)d_in[4];
  const float* bn  = (const float*)d_in[5];
  const float* We  = (const float*)d_in[6];
  const float* be  = (const float*)d_in[7];
  const float* Wc  = (const float*)d_in[8];
  const float* bc  = (const float*)d_in[9];
  const float* Wo  = (const float*)d_in[10];
  const float* bo  = (const float*)d_in[11];
  float* out = (float*)d_out;

  float* acc = (float*)d_ws;                      // [N, H] node_emb + messages
  float* T2  = acc + (size_t)N_NODES * H;         // [N, H] node part of msg (+ b_conv)
  int*   flag = (int*)(T2 + (size_t)N_NODES * H); // int-width detection flag

  detect_kernel<<<1, 64, 0, stream>>>(eidx, flag);
  node_kernel<<<1024, 256, 0, stream>>>(nf, Wn, bn, Wc, bc, acc, T2);
  edge_kernel<<<2048, 256, 0, stream>>>(eidx, ea, We, be, Wc, T2, acc, flag);
  out_kernel<<<(N_POSTS + 3) / 4, 256, 0, stream>>>(pidx, acc, Wo, bo, out, flag);
}

// Round 2
// 509.052 us; speedup vs baseline: 2.2328x; 2.2328x over previous
//
#include <hip/hip_runtime.h>
#include <hip/hip_bf16.h>
#include <math.h>

#define N_NODES 100000
#define N_EDGES 1600000
#define N_POSTS 10000
#define ND 128
#define H 64
#define NT (N_EDGES / 16)

typedef __attribute__((ext_vector_type(8))) short bf16x8;
typedef __attribute__((ext_vector_type(4))) float f32x4;

static __device__ __forceinline__ unsigned short f2bf(float f) {
  return __builtin_bit_cast(unsigned short, __float2bfloat16(f));
}

static __device__ __forceinline__ bf16x8 pack8(const float* v) {
  bf16x8 r;
#pragma unroll
  for (int i = 0; i < 8; ++i) r[i] = (short)f2bf(v[i]);
  return r;
}

__device__ __forceinline__ float bcastf(float v, int lane) {
  return __builtin_bit_cast(float, __builtin_amdgcn_readlane(__builtin_bit_cast(int, v), lane));
}

__device__ __forceinline__ int load_idx(const void* p, long long i, int is64) {
  if (is64) return (int)((const long long*)p)[i];
  return ((const int*)p)[i];
}

// Detect whether integer inputs arrived as int64 (odd 32-bit words all zero)
__global__ void detect_kernel(const void* __restrict__ eidx, int* __restrict__ flag) {
  int t = threadIdx.x; // 64 threads
  int v = ((const int*)eidx)[2 * t + 1];
  unsigned long long b = __ballot(v != 0);
  if (t == 0) flag[0] = (b == 0ULL) ? 1 : 0; // 1 => int64 layout
}

// Per-node: node_emb = relu(nf @ Wn.T + bn); T2 = node_emb @ Wc[:, :H].T + bc
// acc <- node_emb (messages accumulate into it), T2 stored separately.
__global__ void __launch_bounds__(256, 2) node_kernel(
    const float* __restrict__ nf, const float* __restrict__ Wn,
    const float* __restrict__ bn, const float* __restrict__ Wc,
    const float* __restrict__ bc, float* __restrict__ acc,
    float* __restrict__ T2) {
  const int lane = threadIdx.x & 63;
  const int wid = blockIdx.x * (blockDim.x >> 6) + (threadIdx.x >> 6);
  const int nw = gridDim.x * (blockDim.x >> 6);

  float wn[ND]; // W_node row `lane` (lane j owns output channel j)
#pragma unroll
  for (int i = 0; i < ND / 4; ++i) {
    float4 v = ((const float4*)(Wn + lane * ND))[i];
    wn[4 * i] = v.x; wn[4 * i + 1] = v.y; wn[4 * i + 2] = v.z; wn[4 * i + 3] = v.w;
  }
  float wc[H]; // W_conv row `lane`, first half (node part)
#pragma unroll
  for (int i = 0; i < H / 4; ++i) {
    float4 v = ((const float4*)(Wc + lane * 2 * H))[i];
    wc[4 * i] = v.x; wc[4 * i + 1] = v.y; wc[4 * i + 2] = v.z; wc[4 * i + 3] = v.w;
  }
  const float bnl = bn[lane];
  const float bcl = bc[lane];

  for (int n = wid; n < N_NODES; n += nw) {
    const float xa = nf[(long long)n * ND + lane];
    const float xb = nf[(long long)n * ND + 64 + lane];
    float a0 = 0.f, a1 = 0.f, a2 = 0.f, a3 = 0.f;
#pragma unroll
    for (int k = 0; k < 64; k += 4) {
      a0 = fmaf(bcastf(xa, k + 0), wn[k + 0], a0);
      a1 = fmaf(bcastf(xa, k + 1), wn[k + 1], a1);
      a2 = fmaf(bcastf(xa, k + 2), wn[k + 2], a2);
      a3 = fmaf(bcastf(xa, k + 3), wn[k + 3], a3);
    }
#pragma unroll
    for (int k = 0; k < 64; k += 4) {
      a0 = fmaf(bcastf(xb, k + 0), wn[64 + k + 0], a0);
      a1 = fmaf(bcastf(xb, k + 1), wn[64 + k + 1], a1);
      a2 = fmaf(bcastf(xb, k + 2), wn[64 + k + 2], a2);
      a3 = fmaf(bcastf(xb, k + 3), wn[64 + k + 3], a3);
    }
    float e = fmaxf(a0 + a1 + a2 + a3 + bnl, 0.f);

    float t0 = 0.f, t1 = 0.f, t2 = 0.f, t3 = 0.f;
#pragma unroll
    for (int j = 0; j < 64; j += 4) {
      t0 = fmaf(bcastf(e, j + 0), wc[j + 0], t0);
      t1 = fmaf(bcastf(e, j + 1), wc[j + 1], t1);
      t2 = fmaf(bcastf(e, j + 2), wc[j + 2], t2);
      t3 = fmaf(bcastf(e, j + 3), wc[j + 3], t3);
    }
    float t = t0 + t1 + t2 + t3 + bcl;

    acc[(long long)n * H + lane] = e;
    T2[(long long)n * H + lane] = t;
  }
}

// MFMA edge pipeline: 16 edges per wave-tile.
// GEMM1: D1[ch_h][edge] = We * ea^T (+bias via C-init), relu.
// GEMM2: D2[ch_out][edge] = Wce * he  (he chains lane-locally from D1).
// Epilogue: LDS transpose (stride 17) -> per-edge contiguous atomic row.
__global__ void __launch_bounds__(256, 2) edge_kernel(
    const void* __restrict__ eidx, const float* __restrict__ ea,
    const float* __restrict__ We, const float* __restrict__ be,
    const float* __restrict__ Wc, const float* __restrict__ T2,
    float* __restrict__ acc, const int* __restrict__ flag) {
  __shared__ float lds[4][64 * 17];
  const int lane = threadIdx.x & 63;
  const int wslot = threadIdx.x >> 6;
  float* myl = lds[wslot];
  const int wid = blockIdx.x * 4 + wslot;
  const int nw = gridDim.x * 4;
  const int is64 = flag[0];
  const int e16 = lane & 15; // edge-in-tile
  const int g = lane >> 4;   // k-group / row-group

  // Preload weight fragments (once per persistent wave).
  // k-map (per 32-k step t): element i -> k = (i>>2)*16 + g*4 + (i&3).
  bf16x8 wA[4][2], wC[4][2];
#pragma unroll
  for (int mt = 0; mt < 4; ++mt) {
#pragma unroll
    for (int t = 0; t < 2; ++t) {
      float tmp[8];
      const float* rowA = We + (mt * 16 + e16) * H + t * 32 + g * 4;
      *(f32x4*)(tmp) = *(const f32x4*)(rowA);
      *(f32x4*)(tmp + 4) = *(const f32x4*)(rowA + 16);
      wA[mt][t] = pack8(tmp);
      const float* rowC = Wc + (mt * 16 + e16) * (2 * H) + H + t * 32 + g * 4;
      *(f32x4*)(tmp) = *(const f32x4*)(rowC);
      *(f32x4*)(tmp + 4) = *(const f32x4*)(rowC + 16);
      wC[mt][t] = pack8(tmp);
    }
  }
  f32x4 bias[4];
#pragma unroll
  for (int mt = 0; mt < 4; ++mt)
#pragma unroll
    for (int r = 0; r < 4; ++r) bias[mt][r] = be[mt * 16 + g * 4 + r];

  // Prefetch first tile.
  f32x4 ean[4];
  int srcn = 0, dstn = 0;
  int tile = wid;
  if (tile < NT) {
    const float* base = ea + (long long)(tile * 16 + e16) * H;
#pragma unroll
    for (int t = 0; t < 2; ++t) {
      ean[t * 2] = *(const f32x4*)(base + t * 32 + g * 4);
      ean[t * 2 + 1] = *(const f32x4*)(base + t * 32 + 16 + g * 4);
    }
    srcn = load_idx(eidx, (long long)tile * 16 + e16, is64);
    dstn = load_idx(eidx, (long long)N_EDGES + (long long)tile * 16 + e16, is64);
  }

  for (; tile < NT; tile += nw) {
    f32x4 eac[4];
#pragma unroll
    for (int i = 0; i < 4; ++i) eac[i] = ean[i];
    const int srcc = srcn, dstc = dstn;

    const int tn = tile + nw;
    if (tn < NT) {
      const float* base = ea + (long long)(tn * 16 + e16) * H;
#pragma unroll
      for (int t = 0; t < 2; ++t) {
        ean[t * 2] = *(const f32x4*)(base + t * 32 + g * 4);
        ean[t * 2 + 1] = *(const f32x4*)(base + t * 32 + 16 + g * 4);
      }
      srcn = load_idx(eidx, (long long)tn * 16 + e16, is64);
      dstn = load_idx(eidx, (long long)N_EDGES + (long long)tn * 16 + e16, is64);
    }

    // B1 fragments from edge_attr (fp32 -> bf16)
    bf16x8 b1[2];
#pragma unroll
    for (int t = 0; t < 2; ++t) {
      float tmp[8];
#pragma unroll
      for (int i = 0; i < 4; ++i) {
        tmp[i] = eac[t * 2][i];
        tmp[4 + i] = eac[t * 2 + 1][i];
      }
      b1[t] = pack8(tmp);
    }

    // GEMM1: he = relu(We @ ea^T + be)
    f32x4 d1[4];
#pragma unroll
    for (int mt = 0; mt < 4; ++mt) d1[mt] = bias[mt];
#pragma unroll
    for (int t = 0; t < 2; ++t)
#pragma unroll
      for (int mt = 0; mt < 4; ++mt)
        d1[mt] = __builtin_amdgcn_mfma_f32_16x16x32_bf16(wA[mt][t], b1[t], d1[mt], 0, 0, 0);

    // relu + lane-local chaining into GEMM2's B operand
    bf16x8 b2[2];
#pragma unroll
    for (int t = 0; t < 2; ++t) {
      float tmp[8];
#pragma unroll
      for (int i = 0; i < 4; ++i) {
        tmp[i] = fmaxf(d1[2 * t][i], 0.f);
        tmp[4 + i] = fmaxf(d1[2 * t + 1][i], 0.f);
      }
      b2[t] = pack8(tmp);
    }

    // GEMM2: msg^T = Wce @ he
    f32x4 d2[4];
#pragma unroll
    for (int mt = 0; mt < 4; ++mt) d2[mt] = (f32x4){0.f, 0.f, 0.f, 0.f};
#pragma unroll
    for (int t = 0; t < 2; ++t)
#pragma unroll
      for (int mt = 0; mt < 4; ++mt)
        d2[mt] = __builtin_amdgcn_mfma_f32_16x16x32_bf16(wC[mt][t], b2[t], d2[mt], 0, 0, 0);

    // LDS transpose: lds[ch*17 + edge]  (stride 17 => ~2-way conflicts)
#pragma unroll
    for (int mt = 0; mt < 4; ++mt)
#pragma unroll
      for (int r = 0; r < 4; ++r)
        myl[(mt * 16 + g * 4 + r) * 17 + e16] = d2[mt][r];

    // Scatter: per edge, coalesced T2 gather + contiguous 64-dword atomic row.
#pragma unroll
    for (int e = 0; e < 16; ++e) {
      const int s = __builtin_amdgcn_readlane(srcc, e);
      const int d = __builtin_amdgcn_readlane(dstc, e);
      const float m = myl[lane * 17 + e] + T2[(long long)s * H + lane];
      atomicAdd(&acc[(long long)d * H + lane], m);
    }
  }
}

// Per-post: logit = dot(acc[idx], W_out) + b_out; out = sigmoid(logit)
__global__ void __launch_bounds__(256) out_kernel(
    const void* __restrict__ pidx, const float* __restrict__ acc,
    const float* __restrict__ Wo, const float* __restrict__ bo,
    float* __restrict__ out, const int* __restrict__ flag) {
  const int lane = threadIdx.x & 63;
  const int w = blockIdx.x * (blockDim.x >> 6) + (threadIdx.x >> 6);
  if (w >= N_POSTS) return;
  const int is64 = flag[0];
  const int idx = load_idx(pidx, w, is64);
  float v = acc[(long long)idx * H + lane] * Wo[lane];
#pragma unroll
  for (int s = 32; s > 0; s >>= 1) v += __shfl_xor(v, s, 64);
  if (lane == 0) {
    float logit = v + bo[0];
    out[w] = 1.f / (1.f + expf(-logit));
  }
}

extern "C" void kernel_launch(void* const* d_in, const int* in_sizes, int n_in,
                              void* d_out, int out_size, void* d_ws, size_t ws_size,
                              hipStream_t stream) {
  const float* nf = (const float*)d_in[0];
  const void* eidx = d_in[1];
  const float* ea = (const float*)d_in[2];
  const void* pidx = d_in[3];
  const float* Wn = (const float*)d_in[4];
  const float* bn = (const float*)d_in[5];
  const float* We = (const float*)d_in[6];
  const float* be = (const float*)d_in[7];
  const float* Wc = (const float*)d_in[8];
  const float* bc = (const float*)d_in[9];
  const float* Wo = (const float*)d_in[10];
  const float* bo = (const float*)d_in[11];
  float* out = (float*)d_out;

  float* acc = (float*)d_ws;                      // [N, H] node_emb + messages
  float* T2 = acc + (size_t)N_NODES * H;          // [N, H] node part of msg (+ b_conv)
  int* flag = (int*)(T2 + (size_t)N_NODES * H);   // int-width detection flag

  detect_kernel<<<1, 64, 0, stream>>>(eidx, flag);
  node_kernel<<<1024, 256, 0, stream>>>(nf, Wn, bn, Wc, bc, acc, T2);
  edge_kernel<<<1024, 256, 0, stream>>>(eidx, ea, We, be, Wc, T2, acc, flag);
  out_kernel<<<(N_POSTS + 3) / 4, 256, 0, stream>>>(pidx, acc, Wo, bo, out, flag);
}